// Round 1
// 117.672 us; speedup vs baseline: 1.1119x; 1.1119x over previous
//
#include <hip/hip_runtime.h>

#define HID 768
#define NTHREADS 256
#define WPB 4          // waves per block = steps processed in parallel per token
#define RTHREADS 256   // reduce kernel block size

// One block per token t; wave w handles path steps d = w, w+4, w+8, ...
// h[t] is loaded ONCE into registers (12 VGPRs/lane, L1 dedupes across the
// block's 4 waves) instead of once per (t,d) wave as before (-85 MB of L2
// traffic). W rows are double-buffered: the next step's 6 float4 loads are
// issued before the current step's butterfly+CE, keeping >=6 loads in
// flight per wave. Validity is a prefix in d, so the walk stops at the
// first invalid step; the speculative prefetch clamps to node 0 (L2-hot).
// Partials: one float per wave = T*WPB slots (was T*ceil(D/4)*WPB).
__global__ __launch_bounds__(NTHREADS) void huffman_token_kernel(
    const float* __restrict__ hidden,       // [T, H]
    const int*   __restrict__ target,       // [T]
    const float* __restrict__ node_W,       // [V-1, H, 2]
    const float* __restrict__ node_b,       // [V-1, 2]
    const int*   __restrict__ path_nodes,   // [V, D]
    const int*   __restrict__ path_bits,    // [V, D]
    const void*  __restrict__ path_mask,    // [V, D] bool (byte OR int32 layout)
    float*       __restrict__ partial,      // [T * WPB]
    int D)
{
    const int t    = blockIdx.x;
    const int wave = threadIdx.x >> 6;
    const int lane = threadIdx.x & 63;

    // Mask layout detect: mask[0,0..3] all true (min Huffman depth >> 4),
    // so byte layout reads 0x01010101, int32 layout reads 1.
    const bool mask_is_byte = (*(const unsigned int*)path_mask) > 1u;
    const unsigned char* __restrict__ mb = (const unsigned char*)path_mask;
    const int*           __restrict__ mi = (const int*)path_mask;

    const int v = target[t];                     // block-uniform scalar

    // h[t] into registers: lane owns k-pairs p = j*64 + lane (k = 2p, 2p+1).
    const float2* __restrict__ h2 = (const float2*)(hidden + (long)t * HID);
    float2 h[6];
    #pragma unroll
    for (int j = 0; j < 6; ++j) h[j] = h2[j * 64 + lane];

    float sum = 0.0f;

    int  d    = wave;
    long prow = (long)v * D + wave;

    bool valid = (d < D) && (mask_is_byte ? (mb[prow] != 0) : (mi[prow] != 0));
    int  n     = valid ? path_nodes[prow] : 0;

    // Preload W for the first step.
    const float4* __restrict__ w4 = (const float4*)(node_W + (long)n * (HID * 2));
    float4 w[6];
    #pragma unroll
    for (int j = 0; j < 6; ++j) w[j] = w4[j * 64 + lane];

    while (valid) {
        // ---- prefetch next step's node + W row (clamped to row 0 if done) ----
        const long prow2  = prow + WPB;
        const int  d2     = d + WPB;
        const bool valid2 = (d2 < D) &&
            (mask_is_byte ? (mb[prow2] != 0) : (mi[prow2] != 0));
        const int  n2     = valid2 ? path_nodes[prow2] : 0;
        const float4* __restrict__ w4n =
            (const float4*)(node_W + (long)n2 * (HID * 2));
        float4 wn[6];
        #pragma unroll
        for (int j = 0; j < 6; ++j) wn[j] = w4n[j * 64 + lane];

        // ---- compute current step ----
        float acc0 = 0.0f, acc1 = 0.0f;
        #pragma unroll
        for (int j = 0; j < 6; ++j) {                // w = W[n,2p,{0,1}],W[n,2p+1,{0,1}]
            acc0 += h[j].x * w[j].x + h[j].y * w[j].z;
            acc1 += h[j].x * w[j].y + h[j].y * w[j].w;
        }
        #pragma unroll
        for (int off = 32; off > 0; off >>= 1) {
            acc0 += __shfl_xor(acc0, off, 64);
            acc1 += __shfl_xor(acc1, off, 64);
        }

        // Double-softmax CE (faithful to reference), computed redundantly per lane.
        const float l0  = acc0 + node_b[n * 2 + 0];
        const float l1  = acc1 + node_b[n * 2 + 1];
        const float m   = fmaxf(l0, l1);
        const float e0  = __expf(l0 - m);
        const float e1  = __expf(l1 - m);
        const float s   = e0 + e1;
        const float p0  = e0 / s;
        const float p1  = e1 / s;
        const float lse = __logf(__expf(p0) + __expf(p1));
        const float pb  = path_bits[prow] ? p1 : p0;
        sum += lse - pb;

        // ---- rotate double buffer ----
        prow = prow2; d = d2; n = n2; valid = valid2;
        #pragma unroll
        for (int j = 0; j < 6; ++j) w[j] = wn[j];
    }

    if (lane == 0) partial[t * WPB + wave] = sum;   // every slot written (ws is poisoned)
}

// Single-block reduce of n floats (n % 4 == 0) -> out[0].
__global__ __launch_bounds__(RTHREADS) void huffman_reduce_kernel(
    const float* __restrict__ partial, float* __restrict__ out, int n4)
{
    const float4* __restrict__ p4 = (const float4*)partial;
    float s = 0.0f;
    for (int i = threadIdx.x; i < n4; i += RTHREADS) {
        const float4 v = p4[i];
        s += (v.x + v.y) + (v.z + v.w);
    }
    #pragma unroll
    for (int off = 32; off > 0; off >>= 1) s += __shfl_xor(s, off, 64);
    __shared__ float ws[RTHREADS / 64];
    if ((threadIdx.x & 63) == 0) ws[threadIdx.x >> 6] = s;
    __syncthreads();
    if (threadIdx.x == 0) {
        float tot = 0.0f;
        #pragma unroll
        for (int w = 0; w < RTHREADS / 64; ++w) tot += ws[w];
        out[0] = tot;
    }
}

extern "C" void kernel_launch(void* const* d_in, const int* in_sizes, int n_in,
                              void* d_out, int out_size, void* d_ws, size_t ws_size,
                              hipStream_t stream) {
    const float* hidden     = (const float*)d_in[0];
    const int*   target     = (const int*)d_in[1];
    const float* node_W     = (const float*)d_in[2];
    const float* node_b     = (const float*)d_in[3];
    const int*   path_nodes = (const int*)d_in[4];
    const int*   path_bits  = (const int*)d_in[5];
    const void*  path_mask  = (const void*)d_in[6];
    float* out = (float*)d_out;
    float* partial = (float*)d_ws;

    const int T   = in_sizes[0] / HID;        // B*S = 2048 (in_sizes are elem counts)
    const int Vm1 = in_sizes[3] / 2;          // V-1
    const int V   = Vm1 + 1;
    const int D   = in_sizes[4] / V;          // padded path depth (~20)

    const int nslot = T * WPB;                // 8192, multiple of 4

    huffman_token_kernel<<<dim3(T), dim3(NTHREADS), 0, stream>>>(
        hidden, target, node_W, node_b, path_nodes, path_bits, path_mask,
        partial, D);

    huffman_reduce_kernel<<<dim3(1), dim3(RTHREADS), 0, stream>>>(
        partial, out, nslot / 4);
}